// Round 8
// baseline (380.195 us; speedup 1.0000x reference)
//
#include <hip/hip_runtime.h>
#include <math.h>

typedef unsigned short ushort;
typedef short bf16x8 __attribute__((ext_vector_type(8)));
typedef ushort us8 __attribute__((ext_vector_type(8)));
typedef float f32x16 __attribute__((ext_vector_type(16)));
typedef float f32x4 __attribute__((ext_vector_type(4)));

// ---------------- workspace layout (float elements) ----------------
static const size_t OFF_POOLED = 0;         // 4096 f (2 inputs x 2048)
static const size_t OFF_WK     = 4096;      // pooled2 (4096 f)
static const size_t OFF_WT     = 40960;     // Awt 294912 sh = 147456 f
static const size_t OFF_WF     = 188416;    // Wf 32768 sh = 16384 f
static const size_t OFF_AW1    = 204800;    // 9216 sh = 4608 f
static const size_t OFF_AW2    = 209408;    // 5120 sh = 2560 f
static const size_t OFF_T      = 262144;    // bufT 2x8M sh = 8388608 f ; R1 aliases
static const size_t OFF_AB     = 8650752;   // bufAB 2x8M sh = 8388608 f ; bufU aliases
static const size_t OFF_F      = 17039360;  // F 8388608 sh = 4194304 f
// total 21233664 f = 85 MB

static __device__ __forceinline__ ushort f2bf(float f) {
    unsigned int u = __builtin_bit_cast(unsigned int, f);
    u += 0x7FFF + ((u >> 16) & 1);
    return (ushort)(u >> 16);
}
static __device__ __forceinline__ float bf2f(ushort u) {
    return __builtin_bit_cast(float, ((unsigned int)u) << 16);
}

// ---- head: pool (0..4095) + wcomb (4096..4239, LDS-staged GEMM)
//      + awprep (4240) + aw1prep (4241..4276) + aw2prep (4277..4296) --------
// wcomb block (s, mh): out[o_sem, phl, cin_l] = sum_c w2[o_sem,c] * w1-slice.
// w1 reads are COALESCED along w1's native layout (contiguous 144 f per row),
// keeping the 1/9 tap-matching elements via predicated LDS scatter.
// W2s padded to stride 129 -> conflict-free compute reads.
__global__ __launch_bounds__(256) void head_kernel(const float* __restrict__ x1,
                                                   const float* __restrict__ x2,
                                                   float* __restrict__ pooled,
                                                   const float* __restrict__ up_w1,
                                                   const float* __restrict__ up_w2,
                                                   ushort* __restrict__ Awt,
                                                   const float* __restrict__ align_w,
                                                   ushort* __restrict__ Wf,
                                                   const float* __restrict__ re_w1,
                                                   ushort* __restrict__ Aw1,
                                                   const float* __restrict__ re_w2,
                                                   ushort* __restrict__ Aw2) {
    __shared__ float sm[12352];  // 49408 B: wcomb W2s[64*129] + W1s[256*16]; pool r4
    const int bid = blockIdx.x;
    const int t = threadIdx.x;
    if (bid < 4096) {
        // ---- pool ----
        int bc = bid;
        const float* x = (bc >> 11) ? x2 : x1;
        const float4* p = (const float4*)(x + (size_t)(bc & 2047) * 4096);
        float s = 0.f;
        for (int i = t; i < 1024; i += 256) {
            float4 v = p[i];
            s += v.x + v.y + v.z + v.w;
        }
        #pragma unroll
        for (int off = 32; off; off >>= 1) s += __shfl_down(s, off);
        if ((t & 63) == 0) sm[t >> 6] = s;
        __syncthreads();
        if (t == 0) pooled[bc] = (sm[0] + sm[1] + sm[2] + sm[3]) * (1.f / 4096.f);
    } else if (bid < 4240) {
        // ---- wcomb v2 ----
        int w = bid - 4096;
        int mh = (w >= 72) ? 1 : 0;
        int s = w - mh * 72;
        int tap = s >> 3, c16 = s & 7;
        float* W2s = sm;          // [64][129]
        float* W1s = sm + 8256;   // [256][16], row r_idx = c*2 + phl
        for (int i = t; i < 8192; i += 256)
            W2s[(i >> 7) * 129 + (i & 127)] = up_w2[i];
        for (int i = t; i < 36864; i += 256) {
            int r_idx = i / 144;       // 0..255
            int k = i - r_idx * 144;   // 0..143
            int r = ((r_idx >> 1) << 2) + 2 * mh + (r_idx & 1);
            float v = up_w1[(size_t)r * 1152 + c16 * 144 + k];
            int cin_l = k / 9;
            int tp = k - cin_l * 9;
            if (tp == tap) W1s[r_idx * 16 + cin_l] = v;
        }
        __syncthreads();
        float accv[8];
        int wb[8], xb[8];
        #pragma unroll
        for (int oi = 0; oi < 8; oi++) {
            accv[oi] = 0.f;
            int L8 = oi * 256 + t;
            int j = L8 & 7;
            int lane = (L8 >> 3) & 63;
            int mt = (L8 >> 9) & 3;
            int arow = lane & 31;
            int o_sem = (mt & 1) * 32 + (arow & 3) + 4 * ((arow >> 3) & 3) + 16 * ((arow >> 2) & 1);
            wb[oi] = o_sem * 129;
            xb[oi] = (mt >> 1) * 16 + ((lane >> 5) << 3) + j;
        }
        #pragma unroll 4
        for (int c = 0; c < 128; c++) {
            #pragma unroll
            for (int oi = 0; oi < 8; oi++)
                accv[oi] += W2s[wb[oi] + c] * W1s[c * 32 + xb[oi]];
        }
        #pragma unroll
        for (int oi = 0; oi < 8; oi++)
            Awt[(size_t)s * 4096 + mh * 2048 + oi * 256 + t] = f2bf(accv[oi]);
    } else if (bid == 4240) {
        // ---- awprep: Wf [step(16)][mt(4)][lane(64)][8] ----
        #pragma unroll 1
        for (int i = 0; i < 16; i++) {
            int tk = t + (i << 8);
            int step = tk >> 8, mt = (tk >> 6) & 3, lane = tk & 63;
            int o = mt * 32 + (lane & 31);
            int cb = step * 16 + (lane >> 5) * 8;
            #pragma unroll
            for (int j = 0; j < 8; j++) Wf[(size_t)tk * 8 + j] = f2bf(align_w[o * 256 + cb + j]);
        }
    } else if (bid < 4277) {
        // ---- aw1prep ----
        int idx = (bid - 4241) * 256 + t;  // < 9216
        if (idx < 9216) {
            int j = idx & 7, lane = (idx >> 3) & 63, s = idx >> 9;
            int m = lane & 15, kq = lane >> 4;
            int tap = s >> 1, ch = s & 1;
            int cin = ch * 32 + kq * 8 + j;
            float v = (m < 8) ? re_w1[((size_t)(m * 64 + cin)) * 9 + tap] : 0.f;
            Aw1[idx] = f2bf(v);
        }
    } else {
        // ---- aw2prep ----
        int idx = (bid - 4277) * 256 + t;  // < 5120
        if (idx < 5120) {
            int j = idx & 7, lane = (idx >> 3) & 63, mt = (idx >> 9) & 1, s = idx >> 10;
            int m = mt * 32 + (lane & 31), half = lane >> 5;
            int k = s * 16 + half * 8 + j;
            int tap = k >> 3, c = k & 7;
            float v = (tap < 9) ? re_w2[((size_t)(m * 8 + c)) * 9 + tap] : 0.f;
            Aw2[idx] = f2bf(v);
        }
    }
}

// -------- dsc1: f32 in, bf16 out, relu+pool, wk computed inline -------------
__global__ __launch_bounds__(256) void dsc1_kernel(const float* __restrict__ x1,
                                                   const float* __restrict__ x2,
                                                   const float* __restrict__ pooled,
                                                   const float* __restrict__ w1,
                                                   const float* __restrict__ w2,
                                                   ushort* __restrict__ y,
                                                   float* __restrict__ pooled2) {
    int bc = blockIdx.x;  // 4096
    const float* xp = ((bc >> 11) ? x2 : x1) + (size_t)(bc & 2047) * 4096;
    ushort* yp = y + (size_t)bc * 4096;
    __shared__ float tile[66 * 66];
    __shared__ float r4[4];
    __shared__ float sp[128];
    __shared__ float sh[16];
    __shared__ float lgs[9];
    int t = threadIdx.x;
    if (t < 128) sp[t] = pooled[(bc >> 7) * 128 + t];
    for (int i = t; i < 66 * 66; i += 256) tile[i] = 0.f;
    __syncthreads();
    // gelu(pooled @ w1^T) by lanes 0..15, overlapped with tile fill
    if (t < 16) {
        float a = 0.f;
        #pragma unroll 4
        for (int c = 0; c < 128; c++) a += w1[t * 128 + c] * sp[c];
        sh[t] = 0.5f * a * (1.f + erff(a * 0.70710678118654752f));
    }
    const float4* xp4 = (const float4*)xp;
    for (int i = t; i < 1024; i += 256) {
        float4 v = xp4[i];
        int h = i >> 4, w = (i & 15) * 4;
        float* d = &tile[(h + 1) * 66 + w + 1];
        d[0] = v.x; d[1] = v.y; d[2] = v.z; d[3] = v.w;
    }
    __syncthreads();
    if (t < 9) {
        float a = 0.f;
        const float* wr = w2 + (size_t)((bc & 127) * 9 + t) * 16;
        #pragma unroll
        for (int r = 0; r < 16; r++) a += wr[r] * sh[r];
        lgs[t] = a;
    }
    __syncthreads();
    float kk[9];
    {
        float m = -INFINITY;
        #pragma unroll
        for (int k = 0; k < 9; k++) m = fmaxf(m, lgs[k]);
        float se = 0.f;
        #pragma unroll
        for (int k = 0; k < 9; k++) { kk[k] = expf(lgs[k] - m); se += kk[k]; }
        float inv = 1.f / se;
        #pragma unroll
        for (int k = 0; k < 9; k++) kk[k] *= inv;
    }
    float psum = 0.f;
    for (int i = t * 2; i < 4096; i += 512) {
        int h = i >> 6, w = i & 63;
        const float* c = &tile[h * 66 + w];
        float v0 = kk[0]*c[0] + kk[1]*c[1] + kk[2]*c[2]
                 + kk[3]*c[66] + kk[4]*c[67] + kk[5]*c[68]
                 + kk[6]*c[132] + kk[7]*c[133] + kk[8]*c[134] + c[67];
        float v1 = kk[0]*c[1] + kk[1]*c[2] + kk[2]*c[3]
                 + kk[3]*c[67] + kk[4]*c[68] + kk[5]*c[69]
                 + kk[6]*c[133] + kk[7]*c[134] + kk[8]*c[135] + c[68];
        v0 = fmaxf(v0, 0.f); v1 = fmaxf(v1, 0.f);
        psum += v0 + v1;
        ushort2 pk = {f2bf(v0), f2bf(v1)};
        *(ushort2*)&yp[i] = pk;
    }
    #pragma unroll
    for (int off = 32; off; off >>= 1) psum += __shfl_down(psum, off);
    if ((t & 63) == 0) r4[t >> 6] = psum;
    __syncthreads();
    if (t == 0) pooled2[bc] = (r4[0] + r4[1] + r4[2] + r4[3]) * (1.f / 4096.f);
}

// -------- dsc2: bf16 in, bf16 out, wk computed inline -----------------------
__global__ __launch_bounds__(256) void dsc2_kernel(const ushort* __restrict__ x,
                                                   const float* __restrict__ pooled,
                                                   const float* __restrict__ w1,
                                                   const float* __restrict__ w2,
                                                   ushort* __restrict__ y) {
    int bc = blockIdx.x;  // 4096
    const ushort* xp = x + (size_t)bc * 4096;
    ushort* yp = y + (size_t)bc * 4096;
    __shared__ float tile[66 * 66];
    __shared__ float sp[128];
    __shared__ float sh[16];
    __shared__ float lgs[9];
    int t = threadIdx.x;
    if (t < 128) sp[t] = pooled[(bc >> 7) * 128 + t];
    for (int i = t; i < 66 * 66; i += 256) tile[i] = 0.f;
    __syncthreads();
    if (t < 16) {
        float a = 0.f;
        #pragma unroll 4
        for (int c = 0; c < 128; c++) a += w1[t * 128 + c] * sp[c];
        sh[t] = 0.5f * a * (1.f + erff(a * 0.70710678118654752f));
    }
    for (int i = t; i < 512; i += 256) {
        int4 raw = *(const int4*)&xp[i * 8];
        const ushort* u = (const ushort*)&raw;
        int h = i >> 3, w = (i & 7) * 8;
        float* d = &tile[(h + 1) * 66 + w + 1];
        #pragma unroll
        for (int j = 0; j < 8; j++) d[j] = bf2f(u[j]);
    }
    __syncthreads();
    if (t < 9) {
        float a = 0.f;
        const float* wr = w2 + (size_t)((bc & 127) * 9 + t) * 16;
        #pragma unroll
        for (int r = 0; r < 16; r++) a += wr[r] * sh[r];
        lgs[t] = a;
    }
    __syncthreads();
    float kk[9];
    {
        float m = -INFINITY;
        #pragma unroll
        for (int k = 0; k < 9; k++) m = fmaxf(m, lgs[k]);
        float se = 0.f;
        #pragma unroll
        for (int k = 0; k < 9; k++) { kk[k] = expf(lgs[k] - m); se += kk[k]; }
        float inv = 1.f / se;
        #pragma unroll
        for (int k = 0; k < 9; k++) kk[k] *= inv;
    }
    for (int i = t * 2; i < 4096; i += 512) {
        int h = i >> 6, w = i & 63;
        const float* c = &tile[h * 66 + w];
        float v0 = kk[0]*c[0] + kk[1]*c[1] + kk[2]*c[2]
                 + kk[3]*c[66] + kk[4]*c[67] + kk[5]*c[68]
                 + kk[6]*c[132] + kk[7]*c[133] + kk[8]*c[134] + c[67];
        float v1 = kk[0]*c[1] + kk[1]*c[2] + kk[2]*c[3]
                 + kk[3]*c[67] + kk[4]*c[68] + kk[5]*c[69]
                 + kk[6]*c[133] + kk[7]*c[134] + kk[8]*c[135] + c[68];
        ushort2 pk = {f2bf(v0), f2bf(v1)};
        *(ushort2*)&yp[i] = pk;
    }
}

// ---- align: F[b][px][128c] = W @ concat(A,B), bf16 MFMA --------------------
__global__ __launch_bounds__(256, 2) void align_mfma_kernel(const ushort* __restrict__ A,
                                                            const ushort* __restrict__ Bv,
                                                            const ushort* __restrict__ Wf,
                                                            ushort* __restrict__ F) {
    __shared__ ushort Xs[2 * 128 * 8];
    const int b = blockIdx.y;
    const int px0 = blockIdx.x << 7;
    const int tid = threadIdx.x;
    const int wave = tid >> 6, lane = tid & 63;
    const int l31 = lane & 31, half = lane >> 5;

    f32x16 acc[4];
    #pragma unroll
    for (int mt = 0; mt < 4; mt++)
        #pragma unroll
        for (int r = 0; r < 16; r++) acc[mt][r] = 0.f;

    const int cg0 = tid >> 7, pxs0 = tid & 127;
    const int bfofs = (wave * 32 + l31) * 8 + half * 1024;

    for (int step = 0; step < 16; step++) {
        const ushort* src =
            (step < 8 ? A : Bv) + (((size_t)(b * 128 + (step & 7) * 16)) << 12) + px0;
        if (step) __syncthreads();
        #pragma unroll
        for (int q = 0; q < 2; q++) {
            int cg = cg0 + q * 2, px = pxs0;
            ushort v0 = src[((size_t)(cg * 4 + 0) << 12) + px];
            ushort v1 = src[((size_t)(cg * 4 + 1) << 12) + px];
            ushort v2 = src[((size_t)(cg * 4 + 2) << 12) + px];
            ushort v3 = src[((size_t)(cg * 4 + 3) << 12) + px];
            ushort4 pk = {v0, v1, v2, v3};
            *(ushort4*)&Xs[(cg >> 1) * 1024 + px * 8 + (cg & 1) * 4] = pk;
        }
        __syncthreads();
        bf16x8 bfrag = *(const bf16x8*)&Xs[bfofs];
        const bf16x8* wf = (const bf16x8*)(Wf + ((size_t)step * 4 * 64 + lane) * 8);
        #pragma unroll
        for (int mt = 0; mt < 4; mt++)
            acc[mt] = __builtin_amdgcn_mfma_f32_32x32x16_bf16(wf[mt * 64], bfrag, acc[mt], 0, 0, 0);
    }
    // epilogue: F[b][px][c]; o = mt*32 + half*4 + 8*g + i
    ushort* fp = F + ((size_t)(b * 4096 + px0 + wave * 32 + l31)) * 128;
    #pragma unroll
    for (int mt = 0; mt < 4; mt++) {
        #pragma unroll
        for (int g = 0; g < 4; g++) {
            ushort4 pk = {f2bf(acc[mt][g * 4 + 0]), f2bf(acc[mt][g * 4 + 1]),
                          f2bf(acc[mt][g * 4 + 2]), f2bf(acc[mt][g * 4 + 3])};
            *(ushort4*)(fp + mt * 32 + half * 4 + 8 * g) = pk;
        }
    }
}

// ------ up-conv: implicit GEMM 32x32x16 bf16, F[b,px,c] -> U[b,Y,X,64] ------
// 512 threads / 8 waves, acc[2][2] = 64 AGPR per wave, (512,4) -> 4 waves/SIMD.
// Wave (mh = w>>2, bmt = (w>>1)&1, nh = w&1) owns op-quarter x px-half.
// A: distance-2 global ping-pong; B: distance-2 swizzled-LDS ping-pong.
// Direct-store epilogue (wcomb semantic reorder). No barriers in main loop.
__global__ __launch_bounds__(512, 4) void up_mfma_kernel(const ushort* __restrict__ F,
                                                         const ushort* __restrict__ Awt,
                                                         ushort* __restrict__ U) {
    __shared__ ushort Xs[180 * 128];  // 46080 B
    const int b = blockIdx.y;
    const int tr = blockIdx.x >> 3, tc = blockIdx.x & 7;
    const int tid = threadIdx.x;
    const int wave = tid >> 6, lane = tid & 63;
    const int l31 = lane & 31, half = lane >> 5;
    const int mh = wave >> 2, bmt = (wave >> 1) & 1, nh = wave & 1;

    // stage whole 18x10 halo x 128c; unit q stored at slot q ^ (px&7)
    for (int idx = tid; idx < 2880; idx += 512) {
        int px = idx >> 4, q = idx & 15;
        int r = px / 10, c = px - r * 10;
        int gh = tr * 16 - 1 + r, gw = tc * 8 - 1 + c;
        int4 v = {0, 0, 0, 0};
        if ((unsigned)gh < 64u && (unsigned)gw < 64u)
            v = *(const int4*)(F + ((size_t)(b * 4096 + gh * 64 + gw)) * 128 + q * 8);
        *(int4*)&Xs[px * 128 + ((q ^ (px & 7)) << 3)] = v;
    }
    __syncthreads();

    f32x16 acc[2][2];
    #pragma unroll
    for (int mt = 0; mt < 2; mt++)
        #pragma unroll
        for (int nt = 0; nt < 2; nt++)
            #pragma unroll
            for (int r = 0; r < 16; r++) acc[mt][nt][r] = 0.f;

    int xpos[2];
    #pragma unroll
    for (int nt = 0; nt < 2; nt++) {
        int pxl = nh * 64 + nt * 32 + l31;
        xpos[nt] = (pxl >> 3) * 10 + (pxl & 7);
    }

    // A stream: element offset (s*8 + mh*4 + bmt*2 + mtl)*512 + lane*8
    const ushort* abase = Awt + (size_t)(mh * 4 + bmt * 2) * 512 + lane * 8;

    #define LDA(ss, mtl) (*(const bf16x8*)(abase + (size_t)(ss) * 4096 + (mtl) * 512))
    #define LDB(ss, nt) ({                                                   \
        int tap_ = (ss) >> 3, c16_ = (ss) & 7;                               \
        int ky_ = (tap_ * 11) >> 5;  /* tap/3 for 0..8 */                    \
        int kx_ = tap_ - ky_ * 3;                                            \
        int p_ = xpos[nt] + ky_ * 10 + kx_;                                  \
        int qq_ = c16_ * 2 + half;                                           \
        *(const bf16x8*)&Xs[p_ * 128 + ((qq_ ^ (p_ & 7)) << 3)];             \
    })

    bf16x8 A0[2], A1[2], B0[2], B1[2];
    A0[0] = LDA(0, 0); A0[1] = LDA(0, 1);
    A1[0] = LDA(1, 0); A1[1] = LDA(1, 1);
    B0[0] = LDB(0, 0); B0[1] = LDB(0, 1);
    B1[0] = LDB(1, 0); B1[1] = LDB(1, 1);

    #define SUBSTEP(ASET, BSET, sn)                                                  \
    {                                                                                \
        _Pragma("unroll")                                                            \
        for (int mt = 0; mt < 2; mt++) {                                             \
            acc[mt][0] = __builtin_amdgcn_mfma_f32_32x32x16_bf16(ASET[mt], BSET[0], acc[mt][0], 0, 0, 0); \
            acc[mt][1] = __builtin_amdgcn_mfma_f32_32x32x16_bf16(ASET[mt], BSET[1], acc[mt][1], 0, 0, 0); \
        }                                                                            \
        ASET[0] = LDA(sn, 0); ASET[1] = LDA(sn, 1);                                  \
        BSET[0] = LDB(sn, 0); BSET[1] = LDB(sn, 1);                                  \
    }

    #pragma unroll 2
    for (int s = 0; s < 70; s += 2) {
        SUBSTEP(A0, B0, s + 2)
        int s3 = (s + 3 < 72) ? s + 3 : 0;
        SUBSTEP(A1, B1, s3)
    }
    // s = 70, 71 (prefetches above were clamped; just consume)
    #pragma unroll
    for (int mt = 0; mt < 2; mt++) {
        acc[mt][0] = __builtin_amdgcn_mfma_f32_32x32x16_bf16(A0[mt], B0[0], acc[mt][0], 0, 0, 0);
        acc[mt][1] = __builtin_amdgcn_mfma_f32_32x32x16_bf16(A0[mt], B0[1], acc[mt][1], 0, 0, 0);
    }
    #pragma unroll
    for (int mt = 0; mt < 2; mt++) {
        acc[mt][0] = __builtin_amdgcn_mfma_f32_32x32x16_bf16(A1[mt], B1[0], acc[mt][0], 0, 0, 0);
        acc[mt][1] = __builtin_amdgcn_mfma_f32_32x32x16_bf16(A1[mt], B1[1], acc[mt][1], 0, 0, 0);
    }
    #undef SUBSTEP
    #undef LDA
    #undef LDB

    // direct epilogue: per (mtl,nt) two 16B stores of 8 consecutive channels
    // global mt = bmt*2 + mtl; Y = 2*(tr*16+h)+mh, X = 2*(tc*8+w)+bmt,
    // ch = 32*mtl + 16*half + r
    #pragma unroll
    for (int nt = 0; nt < 2; nt++) {
        int pxl = nh * 64 + nt * 32 + l31;
        int Y = 2 * (tr * 16 + (pxl >> 3)) + mh;
        int X = 2 * (tc * 8 + (pxl & 7)) + bmt;
        #pragma unroll
        for (int mt = 0; mt < 2; mt++) {
            ushort* up = U + ((size_t)((b * 128 + Y) * 128 + X)) * 64
                       + mt * 32 + half * 16;
            us8 p0, p1;
            #pragma unroll
            for (int i = 0; i < 8; i++) {
                p0[i] = f2bf(acc[mt][nt][i]);
                p1[i] = f2bf(acc[mt][nt][8 + i]);
            }
            *(us8*)up = p0;
            *(us8*)(up + 8) = p1;
        }
    }
}

// ------ re1: conv3x3(U,re_w1)+relu via 16x16x32 MFMA -> R1[b,Y,X,8] ---------
__global__ __launch_bounds__(256, 2) void re1_kernel(const ushort* __restrict__ U,
                                                     const ushort* __restrict__ Aw1,
                                                     ushort* __restrict__ R1) {
    __shared__ ushort Xs[324 * 72];  // 46656 B
    __shared__ ushort As[18 * 64 * 8];
    const int b = blockIdx.y;
    const int ty = blockIdx.x >> 3, tx = blockIdx.x & 7;
    const int tid = threadIdx.x;
    const int wave = tid >> 6, lane = tid & 63;
    const int m16 = lane & 15, kq = lane >> 4;

    for (int idx = tid; idx < 1152; idx += 256)
        *(int4*)&As[idx * 8] = *(const int4*)(Aw1 + (size_t)idx * 8);
    for (int idx = tid; idx < 2592; idx += 256) {
        int px = idx >> 3, q = idx & 7;
        int r = px / 18, c = px - r * 18;
        int gY = ty * 16 - 1 + r, gX = tx * 16 - 1 + c;
        int4 v = {0, 0, 0, 0};
        if ((unsigned)gY < 128u && (unsigned)gX < 128u)
            v = *(const int4*)(U + ((size_t)((b * 128 + gY) * 128 + gX)) * 64 + q * 8);
        *(int4*)&Xs[px * 72 + q * 8] = v;
    }
    __syncthreads();

    f32x4 acc[4];
    #pragma unroll
    for (int nt = 0; nt < 4; nt++)
        #pragma unroll
        for (int r = 0; r < 4; r++) acc[nt][r] = 0.f;

    #pragma unroll 1
    for (int s = 0; s < 18; s++) {
        bf16x8 a = *(const bf16x8*)&As[(s * 64 + lane) * 8];
        int tap = s >> 1, ch = s & 1;
        int ky = tap / 3, kx = tap - ky * 3;
        int xo = (ky * 18 + kx) * 72 + ch * 32 + kq * 8;
        #pragma unroll
        for (int nt = 0; nt < 4; nt++) {
            int row = wave * 4 + nt;
            bf16x8 bv = *(const bf16x8*)&Xs[(row * 18 + m16) * 72 + xo];
            acc[nt] = __builtin_amdgcn_mfma_f32_16x16x32_bf16(a, bv, acc[nt], 0, 0, 0);
        }
    }
    if (kq < 2) {
        #pragma unroll
        for (int nt = 0; nt < 4; nt++) {
            int gY = ty * 16 + wave * 4 + nt, gX = tx * 16 + m16;
            ushort4 pk = {f2bf(fmaxf(acc[nt][0], 0.f)), f2bf(fmaxf(acc[nt][1], 0.f)),
                          f2bf(fmaxf(acc[nt][2], 0.f)), f2bf(fmaxf(acc[nt][3], 0.f))};
            *(ushort4*)(R1 + ((size_t)((b * 128 + gY) * 128 + gX)) * 8 + kq * 4) = pk;
        }
    }
}

// ------ re2: conv3x3(R1,re_w2) + up  via 32x32x16 MFMA -> out f32 planar ----
__global__ __launch_bounds__(256, 2) void re2_kernel(const ushort* __restrict__ R1,
                                                     const ushort* __restrict__ U,
                                                     const ushort* __restrict__ Aw2,
                                                     float* __restrict__ out) {
    __shared__ ushort Xs[324 * 8];   // 5184 B
    __shared__ ushort As[5 * 2 * 64 * 8];
    __shared__ ushort Us[256 * 68];  // 34816 B
    const int b = blockIdx.y;
    const int ty = blockIdx.x >> 3, tx = blockIdx.x & 7;
    const int tid = threadIdx.x;
    const int wave = tid >> 6, lane = tid & 63;
    const int l31 = lane & 31, half = lane >> 5;

    for (int idx = tid; idx < 640; idx += 256)
        *(int4*)&As[idx * 8] = *(const int4*)(Aw2 + (size_t)idx * 8);
    for (int idx = tid; idx < 324; idx += 256) {
        int r = idx / 18, c = idx - r * 18;
        int gY = ty * 16 - 1 + r, gX = tx * 16 - 1 + c;
        int4 v = {0, 0, 0, 0};
        if ((unsigned)gY < 128u && (unsigned)gX < 128u)
            v = *(const int4*)(R1 + ((size_t)((b * 128 + gY) * 128 + gX)) * 8);
        *(int4*)&Xs[idx * 8] = v;
    }
    for (int idx = tid; idx < 2048; idx += 256) {
        int px = idx >> 3, q = idx & 7;
        int gY = ty * 16 + (px >> 4), gX = tx * 16 + (px & 15);
        const ushort* s = U + ((size_t)((b * 128 + gY) * 128 + gX)) * 64 + q * 8;
        ushort4 v0 = *(const ushort4*)s;
        ushort4 v1 = *(const ushort4*)(s + 4);
        *(ushort4*)&Us[px * 68 + q * 8] = v0;
        *(ushort4*)&Us[px * 68 + q * 8 + 4] = v1;
    }
    __syncthreads();

    f32x16 acc[2][2];
    #pragma unroll
    for (int mt = 0; mt < 2; mt++)
        #pragma unroll
        for (int nt = 0; nt < 2; nt++)
            #pragma unroll
            for (int r = 0; r < 16; r++) acc[mt][nt][r] = 0.f;

    #pragma unroll
    for (int s = 0; s < 5; s++) {
        bf16x8 a0 = *(const bf16x8*)&As[((s * 2 + 0) * 64 + lane) * 8];
        bf16x8 a1 = *(const bf16x8*)&As[((s * 2 + 1) * 64 + lane) * 8];
        int t = 2 * s + half;
        if (t > 8) t = 8;  // A is zero there
        int ky = t / 3, kx = t - ky * 3;
        #pragma unroll
        for (int nt = 0; nt < 2; nt++) {
            int pxl = wave * 64 + nt * 32 + l31;
            int row = pxl >> 4, col = pxl & 15;
            bf16x8 bv = *(const bf16x8*)&Xs[((row + ky) * 18 + col + kx) * 8];
            acc[0][nt] = __builtin_amdgcn_mfma_f32_32x32x16_bf16(a0, bv, acc[0][nt], 0, 0, 0);
            acc[1][nt] = __builtin_amdgcn_mfma_f32_32x32x16_bf16(a1, bv, acc[1][nt], 0, 0, 0);
        }
    }
    #pragma unroll
    for (int mt = 0; mt < 2; mt++) {
        #pragma unroll
        for (int nt = 0; nt < 2; nt++) {
            int pxl = wave * 64 + nt * 32 + l31;
            int gY = ty * 16 + (pxl >> 4), gX = tx * 16 + (pxl & 15);
            #pragma unroll
            for (int r = 0; r < 16; r++) {
                int o = mt * 32 + (r & 3) + 8 * (r >> 2) + 4 * half;
                float v = acc[mt][nt][r] + bf2f(Us[pxl * 68 + o]);
                out[((size_t)(b * 64 + o) * 128 + gY) * 128 + gX] = v;
            }
        }
    }
}

extern "C" void kernel_launch(void* const* d_in, const int* in_sizes, int n_in,
                              void* d_out, int out_size, void* d_ws, size_t ws_size,
                              hipStream_t stream) {
    const float* x1      = (const float*)d_in[0];
    const float* x2      = (const float*)d_in[1];
    const float* d1_w1   = (const float*)d_in[2];
    const float* d1_w2   = (const float*)d_in[3];
    const float* d2_w1   = (const float*)d_in[4];
    const float* d2_w2   = (const float*)d_in[5];
    const float* align_w = (const float*)d_in[6];
    const float* up_w1   = (const float*)d_in[7];
    const float* up_w2   = (const float*)d_in[8];
    const float* re_w1   = (const float*)d_in[9];
    const float* re_w2   = (const float*)d_in[10];
    float* out = (float*)d_out;
    float* ws  = (float*)d_ws;

    float*  pooled  = ws + OFF_POOLED;
    float*  pooled2 = ws + OFF_WK;
    ushort* Awt    = (ushort*)(ws + OFF_WT);
    ushort* Wf     = (ushort*)(ws + OFF_WF);
    ushort* Aw1    = (ushort*)(ws + OFF_AW1);
    ushort* Aw2    = (ushort*)(ws + OFF_AW2);
    ushort* bufT   = (ushort*)(ws + OFF_T);
    ushort* R1     = (ushort*)(ws + OFF_T);   // alias (bufT dead by re1)
    ushort* bufAB  = (ushort*)(ws + OFF_AB);
    ushort* bufU   = (ushort*)(ws + OFF_AB);  // alias (bufAB dead after align)
    ushort* F      = (ushort*)(ws + OFF_F);

    head_kernel<<<4297, 256, 0, stream>>>(x1, x2, pooled, up_w1, up_w2, Awt,
                                          align_w, Wf, re_w1, Aw1, re_w2, Aw2);
    dsc1_kernel<<<4096, 256, 0, stream>>>(x1, x2, pooled, d1_w1, d1_w2, bufT, pooled2);
    dsc2_kernel<<<4096, 256, 0, stream>>>(bufT, pooled2, d2_w1, d2_w2, bufAB);

    align_mfma_kernel<<<dim3(32, 16), 256, 0, stream>>>(bufAB, bufAB + 8388608, Wf, F);
    up_mfma_kernel<<<dim3(32, 16), 512, 0, stream>>>(F, Awt, bufU);
    re1_kernel<<<dim3(64, 16), 256, 0, stream>>>(bufU, Aw1, R1);
    re2_kernel<<<dim3(64, 16), 256, 0, stream>>>(R1, bufU, Aw2, out);
}

// Round 9
// 379.738 us; speedup vs baseline: 1.0012x; 1.0012x over previous
//
#include <hip/hip_runtime.h>
#include <math.h>

typedef unsigned short ushort;
typedef short bf16x8 __attribute__((ext_vector_type(8)));
typedef ushort us8 __attribute__((ext_vector_type(8)));
typedef float f32x16 __attribute__((ext_vector_type(16)));
typedef float f32x4 __attribute__((ext_vector_type(4)));

// ---------------- workspace layout (float elements) ----------------
static const size_t OFF_POOLED = 0;         // 4096 f (2 inputs x 2048)
static const size_t OFF_WK     = 4096;      // pooled2 (4096 f)
static const size_t OFF_WT     = 40960;     // Awt 294912 sh = 147456 f
static const size_t OFF_WF     = 188416;    // Wf 32768 sh = 16384 f
static const size_t OFF_AW1    = 204800;    // 9216 sh = 4608 f
static const size_t OFF_AW2    = 209408;    // 5120 sh = 2560 f
static const size_t OFF_T      = 262144;    // bufT 2x8M sh = 8388608 f ; R1 aliases
static const size_t OFF_AB     = 8650752;   // bufAB 2x8M sh = 8388608 f ; bufU aliases
static const size_t OFF_F      = 17039360;  // F 8388608 sh = 4194304 f
// total 21233664 f = 85 MB

static __device__ __forceinline__ ushort f2bf(float f) {
    unsigned int u = __builtin_bit_cast(unsigned int, f);
    u += 0x7FFF + ((u >> 16) & 1);
    return (ushort)(u >> 16);
}
static __device__ __forceinline__ float bf2f(ushort u) {
    return __builtin_bit_cast(float, ((unsigned int)u) << 16);
}

// ---------------- pool: tiny LDS so occupancy stays high --------------------
__global__ __launch_bounds__(256) void pool_kernel(const float* __restrict__ x1,
                                                   const float* __restrict__ x2,
                                                   float* __restrict__ pooled) {
    int bc = blockIdx.x;  // 4096
    const float* x = (bc >> 11) ? x2 : x1;
    const float4* p = (const float4*)(x + (size_t)(bc & 2047) * 4096);
    float s = 0.f;
    for (int i = threadIdx.x; i < 1024; i += 256) {
        float4 v = p[i];
        s += v.x + v.y + v.z + v.w;
    }
    #pragma unroll
    for (int off = 32; off; off >>= 1) s += __shfl_down(s, off);
    __shared__ float r4[4];
    if ((threadIdx.x & 63) == 0) r4[threadIdx.x >> 6] = s;
    __syncthreads();
    if (threadIdx.x == 0) pooled[bc] = (r4[0] + r4[1] + r4[2] + r4[3]) * (1.f / 4096.f);
}

// ---- prep: wcomb v2 (blocks 0..143, LDS-staged GEMM) + awprep (144)
//      + aw1prep (145..180) + aw2prep (181..200) ----------------------------
// wcomb block (s, mh): out[o_sem, phl, cin_l] = sum_c w2[o_sem,c] * w1-slice.
// w1 reads COALESCED along native layout (contiguous 144 f per row), keep the
// 1/9 tap-matching elements via predicated LDS scatter. W2s stride 129.
__global__ __launch_bounds__(256) void prep_kernel(const float* __restrict__ up_w1,
                                                   const float* __restrict__ up_w2,
                                                   ushort* __restrict__ Awt,
                                                   const float* __restrict__ align_w,
                                                   ushort* __restrict__ Wf,
                                                   const float* __restrict__ re_w1,
                                                   ushort* __restrict__ Aw1,
                                                   const float* __restrict__ re_w2,
                                                   ushort* __restrict__ Aw2) {
    __shared__ float sm[12352];  // 49408 B: W2s[64*129] + W1s[256*16]
    const int bid = blockIdx.x;
    const int t = threadIdx.x;
    if (bid < 144) {
        // ---- wcomb v2 ----
        int mh = (bid >= 72) ? 1 : 0;
        int s = bid - mh * 72;
        int tap = s >> 3, c16 = s & 7;
        float* W2s = sm;          // [64][129]
        float* W1s = sm + 8256;   // [256][16], row r_idx = c*2 + phl
        for (int i = t; i < 8192; i += 256)
            W2s[(i >> 7) * 129 + (i & 127)] = up_w2[i];
        for (int i = t; i < 36864; i += 256) {
            int r_idx = i / 144;       // 0..255
            int k = i - r_idx * 144;   // 0..143
            int r = ((r_idx >> 1) << 2) + 2 * mh + (r_idx & 1);
            float v = up_w1[(size_t)r * 1152 + c16 * 144 + k];
            int cin_l = k / 9;
            int tp = k - cin_l * 9;
            if (tp == tap) W1s[r_idx * 16 + cin_l] = v;
        }
        __syncthreads();
        float accv[8];
        int wb[8], xb[8];
        #pragma unroll
        for (int oi = 0; oi < 8; oi++) {
            accv[oi] = 0.f;
            int L8 = oi * 256 + t;
            int j = L8 & 7;
            int lane = (L8 >> 3) & 63;
            int mt = (L8 >> 9) & 3;
            int arow = lane & 31;
            int o_sem = (mt & 1) * 32 + (arow & 3) + 4 * ((arow >> 3) & 3) + 16 * ((arow >> 2) & 1);
            wb[oi] = o_sem * 129;
            xb[oi] = (mt >> 1) * 16 + ((lane >> 5) << 3) + j;
        }
        #pragma unroll 4
        for (int c = 0; c < 128; c++) {
            #pragma unroll
            for (int oi = 0; oi < 8; oi++)
                accv[oi] += W2s[wb[oi] + c] * W1s[c * 32 + xb[oi]];
        }
        #pragma unroll
        for (int oi = 0; oi < 8; oi++)
            Awt[(size_t)s * 4096 + mh * 2048 + oi * 256 + t] = f2bf(accv[oi]);
    } else if (bid == 144) {
        // ---- awprep: Wf [step(16)][mt(4)][lane(64)][8] ----
        #pragma unroll 1
        for (int i = 0; i < 16; i++) {
            int tk = t + (i << 8);
            int step = tk >> 8, mt = (tk >> 6) & 3, lane = tk & 63;
            int o = mt * 32 + (lane & 31);
            int cb = step * 16 + (lane >> 5) * 8;
            #pragma unroll
            for (int j = 0; j < 8; j++) Wf[(size_t)tk * 8 + j] = f2bf(align_w[o * 256 + cb + j]);
        }
    } else if (bid < 181) {
        // ---- aw1prep ----
        int idx = (bid - 145) * 256 + t;  // < 9216
        if (idx < 9216) {
            int j = idx & 7, lane = (idx >> 3) & 63, s = idx >> 9;
            int m = lane & 15, kq = lane >> 4;
            int tap = s >> 1, ch = s & 1;
            int cin = ch * 32 + kq * 8 + j;
            float v = (m < 8) ? re_w1[((size_t)(m * 64 + cin)) * 9 + tap] : 0.f;
            Aw1[idx] = f2bf(v);
        }
    } else {
        // ---- aw2prep ----
        int idx = (bid - 181) * 256 + t;  // < 5120
        if (idx < 5120) {
            int j = idx & 7, lane = (idx >> 3) & 63, mt = (idx >> 9) & 1, s = idx >> 10;
            int m = mt * 32 + (lane & 31), half = lane >> 5;
            int k = s * 16 + half * 8 + j;
            int tap = k >> 3, c = k & 7;
            float v = (tap < 9) ? re_w2[((size_t)(m * 8 + c)) * 9 + tap] : 0.f;
            Aw2[idx] = f2bf(v);
        }
    }
}

// -------- dsc1: f32 in, bf16 out, relu+pool, wk computed inline -------------
__global__ __launch_bounds__(256) void dsc1_kernel(const float* __restrict__ x1,
                                                   const float* __restrict__ x2,
                                                   const float* __restrict__ pooled,
                                                   const float* __restrict__ w1,
                                                   const float* __restrict__ w2,
                                                   ushort* __restrict__ y,
                                                   float* __restrict__ pooled2) {
    int bc = blockIdx.x;  // 4096
    const float* xp = ((bc >> 11) ? x2 : x1) + (size_t)(bc & 2047) * 4096;
    ushort* yp = y + (size_t)bc * 4096;
    __shared__ float tile[66 * 66];
    __shared__ float r4[4];
    __shared__ float sp[128];
    __shared__ float sh[16];
    __shared__ float lgs[9];
    int t = threadIdx.x;
    if (t < 128) sp[t] = pooled[(bc >> 7) * 128 + t];
    for (int i = t; i < 66 * 66; i += 256) tile[i] = 0.f;
    __syncthreads();
    // gelu(pooled @ w1^T) by lanes 0..15, overlapped with tile fill
    if (t < 16) {
        float a = 0.f;
        #pragma unroll 4
        for (int c = 0; c < 128; c++) a += w1[t * 128 + c] * sp[c];
        sh[t] = 0.5f * a * (1.f + erff(a * 0.70710678118654752f));
    }
    const float4* xp4 = (const float4*)xp;
    for (int i = t; i < 1024; i += 256) {
        float4 v = xp4[i];
        int h = i >> 4, w = (i & 15) * 4;
        float* d = &tile[(h + 1) * 66 + w + 1];
        d[0] = v.x; d[1] = v.y; d[2] = v.z; d[3] = v.w;
    }
    __syncthreads();
    if (t < 9) {
        float a = 0.f;
        const float* wr = w2 + (size_t)((bc & 127) * 9 + t) * 16;
        #pragma unroll
        for (int r = 0; r < 16; r++) a += wr[r] * sh[r];
        lgs[t] = a;
    }
    __syncthreads();
    float kk[9];
    {
        float m = -INFINITY;
        #pragma unroll
        for (int k = 0; k < 9; k++) m = fmaxf(m, lgs[k]);
        float se = 0.f;
        #pragma unroll
        for (int k = 0; k < 9; k++) { kk[k] = expf(lgs[k] - m); se += kk[k]; }
        float inv = 1.f / se;
        #pragma unroll
        for (int k = 0; k < 9; k++) kk[k] *= inv;
    }
    float psum = 0.f;
    for (int i = t * 2; i < 4096; i += 512) {
        int h = i >> 6, w = i & 63;
        const float* c = &tile[h * 66 + w];
        float v0 = kk[0]*c[0] + kk[1]*c[1] + kk[2]*c[2]
                 + kk[3]*c[66] + kk[4]*c[67] + kk[5]*c[68]
                 + kk[6]*c[132] + kk[7]*c[133] + kk[8]*c[134] + c[67];
        float v1 = kk[0]*c[1] + kk[1]*c[2] + kk[2]*c[3]
                 + kk[3]*c[67] + kk[4]*c[68] + kk[5]*c[69]
                 + kk[6]*c[133] + kk[7]*c[134] + kk[8]*c[135] + c[68];
        v0 = fmaxf(v0, 0.f); v1 = fmaxf(v1, 0.f);
        psum += v0 + v1;
        ushort2 pk = {f2bf(v0), f2bf(v1)};
        *(ushort2*)&yp[i] = pk;
    }
    #pragma unroll
    for (int off = 32; off; off >>= 1) psum += __shfl_down(psum, off);
    if ((t & 63) == 0) r4[t >> 6] = psum;
    __syncthreads();
    if (t == 0) pooled2[bc] = (r4[0] + r4[1] + r4[2] + r4[3]) * (1.f / 4096.f);
}

// -------- dsc2: bf16 in, bf16 out, wk computed inline -----------------------
__global__ __launch_bounds__(256) void dsc2_kernel(const ushort* __restrict__ x,
                                                   const float* __restrict__ pooled,
                                                   const float* __restrict__ w1,
                                                   const float* __restrict__ w2,
                                                   ushort* __restrict__ y) {
    int bc = blockIdx.x;  // 4096
    const ushort* xp = x + (size_t)bc * 4096;
    ushort* yp = y + (size_t)bc * 4096;
    __shared__ float tile[66 * 66];
    __shared__ float sp[128];
    __shared__ float sh[16];
    __shared__ float lgs[9];
    int t = threadIdx.x;
    if (t < 128) sp[t] = pooled[(bc >> 7) * 128 + t];
    for (int i = t; i < 66 * 66; i += 256) tile[i] = 0.f;
    __syncthreads();
    if (t < 16) {
        float a = 0.f;
        #pragma unroll 4
        for (int c = 0; c < 128; c++) a += w1[t * 128 + c] * sp[c];
        sh[t] = 0.5f * a * (1.f + erff(a * 0.70710678118654752f));
    }
    for (int i = t; i < 512; i += 256) {
        int4 raw = *(const int4*)&xp[i * 8];
        const ushort* u = (const ushort*)&raw;
        int h = i >> 3, w = (i & 7) * 8;
        float* d = &tile[(h + 1) * 66 + w + 1];
        #pragma unroll
        for (int j = 0; j < 8; j++) d[j] = bf2f(u[j]);
    }
    __syncthreads();
    if (t < 9) {
        float a = 0.f;
        const float* wr = w2 + (size_t)((bc & 127) * 9 + t) * 16;
        #pragma unroll
        for (int r = 0; r < 16; r++) a += wr[r] * sh[r];
        lgs[t] = a;
    }
    __syncthreads();
    float kk[9];
    {
        float m = -INFINITY;
        #pragma unroll
        for (int k = 0; k < 9; k++) m = fmaxf(m, lgs[k]);
        float se = 0.f;
        #pragma unroll
        for (int k = 0; k < 9; k++) { kk[k] = expf(lgs[k] - m); se += kk[k]; }
        float inv = 1.f / se;
        #pragma unroll
        for (int k = 0; k < 9; k++) kk[k] *= inv;
    }
    for (int i = t * 2; i < 4096; i += 512) {
        int h = i >> 6, w = i & 63;
        const float* c = &tile[h * 66 + w];
        float v0 = kk[0]*c[0] + kk[1]*c[1] + kk[2]*c[2]
                 + kk[3]*c[66] + kk[4]*c[67] + kk[5]*c[68]
                 + kk[6]*c[132] + kk[7]*c[133] + kk[8]*c[134] + c[67];
        float v1 = kk[0]*c[1] + kk[1]*c[2] + kk[2]*c[3]
                 + kk[3]*c[67] + kk[4]*c[68] + kk[5]*c[69]
                 + kk[6]*c[133] + kk[7]*c[134] + kk[8]*c[135] + c[68];
        ushort2 pk = {f2bf(v0), f2bf(v1)};
        *(ushort2*)&yp[i] = pk;
    }
}

// ---- align: F[b][px][128c] = W @ concat(A,B), bf16 MFMA --------------------
__global__ __launch_bounds__(256, 2) void align_mfma_kernel(const ushort* __restrict__ A,
                                                            const ushort* __restrict__ Bv,
                                                            const ushort* __restrict__ Wf,
                                                            ushort* __restrict__ F) {
    __shared__ ushort Xs[2 * 128 * 8];
    const int b = blockIdx.y;
    const int px0 = blockIdx.x << 7;
    const int tid = threadIdx.x;
    const int wave = tid >> 6, lane = tid & 63;
    const int l31 = lane & 31, half = lane >> 5;

    f32x16 acc[4];
    #pragma unroll
    for (int mt = 0; mt < 4; mt++)
        #pragma unroll
        for (int r = 0; r < 16; r++) acc[mt][r] = 0.f;

    const int cg0 = tid >> 7, pxs0 = tid & 127;
    const int bfofs = (wave * 32 + l31) * 8 + half * 1024;

    for (int step = 0; step < 16; step++) {
        const ushort* src =
            (step < 8 ? A : Bv) + (((size_t)(b * 128 + (step & 7) * 16)) << 12) + px0;
        if (step) __syncthreads();
        #pragma unroll
        for (int q = 0; q < 2; q++) {
            int cg = cg0 + q * 2, px = pxs0;
            ushort v0 = src[((size_t)(cg * 4 + 0) << 12) + px];
            ushort v1 = src[((size_t)(cg * 4 + 1) << 12) + px];
            ushort v2 = src[((size_t)(cg * 4 + 2) << 12) + px];
            ushort v3 = src[((size_t)(cg * 4 + 3) << 12) + px];
            ushort4 pk = {v0, v1, v2, v3};
            *(ushort4*)&Xs[(cg >> 1) * 1024 + px * 8 + (cg & 1) * 4] = pk;
        }
        __syncthreads();
        bf16x8 bfrag = *(const bf16x8*)&Xs[bfofs];
        const bf16x8* wf = (const bf16x8*)(Wf + ((size_t)step * 4 * 64 + lane) * 8);
        #pragma unroll
        for (int mt = 0; mt < 4; mt++)
            acc[mt] = __builtin_amdgcn_mfma_f32_32x32x16_bf16(wf[mt * 64], bfrag, acc[mt], 0, 0, 0);
    }
    // epilogue: F[b][px][c]; o = mt*32 + half*4 + 8*g + i
    ushort* fp = F + ((size_t)(b * 4096 + px0 + wave * 32 + l31)) * 128;
    #pragma unroll
    for (int mt = 0; mt < 4; mt++) {
        #pragma unroll
        for (int g = 0; g < 4; g++) {
            ushort4 pk = {f2bf(acc[mt][g * 4 + 0]), f2bf(acc[mt][g * 4 + 1]),
                          f2bf(acc[mt][g * 4 + 2]), f2bf(acc[mt][g * 4 + 3])};
            *(ushort4*)(fp + mt * 32 + half * 4 + 8 * g) = pk;
        }
    }
}

// ------ up-conv: implicit GEMM 32x32x16 bf16, F[b,px,c] -> U[b,Y,X,64] ------
// 512 threads / 8 waves, acc[2][2] = 64 AGPR per wave, (512,4) -> 4 waves/SIMD.
// Wave (mh = w>>2, bmt = (w>>1)&1, nh = w&1) owns op-quarter x px-half.
// A: distance-2 global ping-pong; B: distance-2 swizzled-LDS ping-pong.
// Direct-store epilogue (wcomb semantic reorder). No barriers in main loop.
__global__ __launch_bounds__(512, 4) void up_mfma_kernel(const ushort* __restrict__ F,
                                                         const ushort* __restrict__ Awt,
                                                         ushort* __restrict__ U) {
    __shared__ ushort Xs[180 * 128];  // 46080 B
    const int b = blockIdx.y;
    const int tr = blockIdx.x >> 3, tc = blockIdx.x & 7;
    const int tid = threadIdx.x;
    const int wave = tid >> 6, lane = tid & 63;
    const int l31 = lane & 31, half = lane >> 5;
    const int mh = wave >> 2, bmt = (wave >> 1) & 1, nh = wave & 1;

    // stage whole 18x10 halo x 128c; unit q stored at slot q ^ (px&7)
    for (int idx = tid; idx < 2880; idx += 512) {
        int px = idx >> 4, q = idx & 15;
        int r = px / 10, c = px - r * 10;
        int gh = tr * 16 - 1 + r, gw = tc * 8 - 1 + c;
        int4 v = {0, 0, 0, 0};
        if ((unsigned)gh < 64u && (unsigned)gw < 64u)
            v = *(const int4*)(F + ((size_t)(b * 4096 + gh * 64 + gw)) * 128 + q * 8);
        *(int4*)&Xs[px * 128 + ((q ^ (px & 7)) << 3)] = v;
    }
    __syncthreads();

    f32x16 acc[2][2];
    #pragma unroll
    for (int mt = 0; mt < 2; mt++)
        #pragma unroll
        for (int nt = 0; nt < 2; nt++)
            #pragma unroll
            for (int r = 0; r < 16; r++) acc[mt][nt][r] = 0.f;

    int xpos[2];
    #pragma unroll
    for (int nt = 0; nt < 2; nt++) {
        int pxl = nh * 64 + nt * 32 + l31;
        xpos[nt] = (pxl >> 3) * 10 + (pxl & 7);
    }

    // A stream: element offset (s*8 + mh*4 + bmt*2 + mtl)*512 + lane*8
    const ushort* abase = Awt + (size_t)(mh * 4 + bmt * 2) * 512 + lane * 8;

    #define LDA(ss, mtl) (*(const bf16x8*)(abase + (size_t)(ss) * 4096 + (mtl) * 512))
    #define LDB(ss, nt) ({                                                   \
        int tap_ = (ss) >> 3, c16_ = (ss) & 7;                               \
        int ky_ = (tap_ * 11) >> 5;  /* tap/3 for 0..8 */                    \
        int kx_ = tap_ - ky_ * 3;                                            \
        int p_ = xpos[nt] + ky_ * 10 + kx_;                                  \
        int qq_ = c16_ * 2 + half;                                           \
        *(const bf16x8*)&Xs[p_ * 128 + ((qq_ ^ (p_ & 7)) << 3)];             \
    })

    bf16x8 A0[2], A1[2], B0[2], B1[2];
    A0[0] = LDA(0, 0); A0[1] = LDA(0, 1);
    A1[0] = LDA(1, 0); A1[1] = LDA(1, 1);
    B0[0] = LDB(0, 0); B0[1] = LDB(0, 1);
    B1[0] = LDB(1, 0); B1[1] = LDB(1, 1);

    #define SUBSTEP(ASET, BSET, sn)                                                  \
    {                                                                                \
        _Pragma("unroll")                                                            \
        for (int mt = 0; mt < 2; mt++) {                                             \
            acc[mt][0] = __builtin_amdgcn_mfma_f32_32x32x16_bf16(ASET[mt], BSET[0], acc[mt][0], 0, 0, 0); \
            acc[mt][1] = __builtin_amdgcn_mfma_f32_32x32x16_bf16(ASET[mt], BSET[1], acc[mt][1], 0, 0, 0); \
        }                                                                            \
        ASET[0] = LDA(sn, 0); ASET[1] = LDA(sn, 1);                                  \
        BSET[0] = LDB(sn, 0); BSET[1] = LDB(sn, 1);                                  \
    }

    #pragma unroll 2
    for (int s = 0; s < 70; s += 2) {
        SUBSTEP(A0, B0, s + 2)
        int s3 = (s + 3 < 72) ? s + 3 : 0;
        SUBSTEP(A1, B1, s3)
    }
    // s = 70, 71 (prefetches above were clamped; just consume)
    #pragma unroll
    for (int mt = 0; mt < 2; mt++) {
        acc[mt][0] = __builtin_amdgcn_mfma_f32_32x32x16_bf16(A0[mt], B0[0], acc[mt][0], 0, 0, 0);
        acc[mt][1] = __builtin_amdgcn_mfma_f32_32x32x16_bf16(A0[mt], B0[1], acc[mt][1], 0, 0, 0);
    }
    #pragma unroll
    for (int mt = 0; mt < 2; mt++) {
        acc[mt][0] = __builtin_amdgcn_mfma_f32_32x32x16_bf16(A1[mt], B1[0], acc[mt][0], 0, 0, 0);
        acc[mt][1] = __builtin_amdgcn_mfma_f32_32x32x16_bf16(A1[mt], B1[1], acc[mt][1], 0, 0, 0);
    }
    #undef SUBSTEP
    #undef LDA
    #undef LDB

    // direct epilogue: per (mtl,nt) two 16B stores of 8 consecutive channels
    // global mt = bmt*2 + mtl; Y = 2*(tr*16+h)+mh, X = 2*(tc*8+w)+bmt,
    // ch = 32*mtl + 16*half + r
    #pragma unroll
    for (int nt = 0; nt < 2; nt++) {
        int pxl = nh * 64 + nt * 32 + l31;
        int Y = 2 * (tr * 16 + (pxl >> 3)) + mh;
        int X = 2 * (tc * 8 + (pxl & 7)) + bmt;
        #pragma unroll
        for (int mt = 0; mt < 2; mt++) {
            ushort* up = U + ((size_t)((b * 128 + Y) * 128 + X)) * 64
                       + mt * 32 + half * 16;
            us8 p0, p1;
            #pragma unroll
            for (int i = 0; i < 8; i++) {
                p0[i] = f2bf(acc[mt][nt][i]);
                p1[i] = f2bf(acc[mt][nt][8 + i]);
            }
            *(us8*)up = p0;
            *(us8*)(up + 8) = p1;
        }
    }
}

// ------ re1: conv3x3(U,re_w1)+relu via 16x16x32 MFMA -> R1[b,Y,X,8] ---------
__global__ __launch_bounds__(256, 2) void re1_kernel(const ushort* __restrict__ U,
                                                     const ushort* __restrict__ Aw1,
                                                     ushort* __restrict__ R1) {
    __shared__ ushort Xs[324 * 72];  // 46656 B
    __shared__ ushort As[18 * 64 * 8];
    const int b = blockIdx.y;
    const int ty = blockIdx.x >> 3, tx = blockIdx.x & 7;
    const int tid = threadIdx.x;
    const int wave = tid >> 6, lane = tid & 63;
    const int m16 = lane & 15, kq = lane >> 4;

    for (int idx = tid; idx < 1152; idx += 256)
        *(int4*)&As[idx * 8] = *(const int4*)(Aw1 + (size_t)idx * 8);
    for (int idx = tid; idx < 2592; idx += 256) {
        int px = idx >> 3, q = idx & 7;
        int r = px / 18, c = px - r * 18;
        int gY = ty * 16 - 1 + r, gX = tx * 16 - 1 + c;
        int4 v = {0, 0, 0, 0};
        if ((unsigned)gY < 128u && (unsigned)gX < 128u)
            v = *(const int4*)(U + ((size_t)((b * 128 + gY) * 128 + gX)) * 64 + q * 8);
        *(int4*)&Xs[px * 72 + q * 8] = v;
    }
    __syncthreads();

    f32x4 acc[4];
    #pragma unroll
    for (int nt = 0; nt < 4; nt++)
        #pragma unroll
        for (int r = 0; r < 4; r++) acc[nt][r] = 0.f;

    #pragma unroll 1
    for (int s = 0; s < 18; s++) {
        bf16x8 a = *(const bf16x8*)&As[(s * 64 + lane) * 8];
        int tap = s >> 1, ch = s & 1;
        int ky = tap / 3, kx = tap - ky * 3;
        int xo = (ky * 18 + kx) * 72 + ch * 32 + kq * 8;
        #pragma unroll
        for (int nt = 0; nt < 4; nt++) {
            int row = wave * 4 + nt;
            bf16x8 bv = *(const bf16x8*)&Xs[(row * 18 + m16) * 72 + xo];
            acc[nt] = __builtin_amdgcn_mfma_f32_16x16x32_bf16(a, bv, acc[nt], 0, 0, 0);
        }
    }
    if (kq < 2) {
        #pragma unroll
        for (int nt = 0; nt < 4; nt++) {
            int gY = ty * 16 + wave * 4 + nt, gX = tx * 16 + m16;
            ushort4 pk = {f2bf(fmaxf(acc[nt][0], 0.f)), f2bf(fmaxf(acc[nt][1], 0.f)),
                          f2bf(fmaxf(acc[nt][2], 0.f)), f2bf(fmaxf(acc[nt][3], 0.f))};
            *(ushort4*)(R1 + ((size_t)((b * 128 + gY) * 128 + gX)) * 8 + kq * 4) = pk;
        }
    }
}

// ------ re2: conv3x3(R1,re_w2) + up  via 32x32x16 MFMA -> out f32 planar ----
__global__ __launch_bounds__(256, 2) void re2_kernel(const ushort* __restrict__ R1,
                                                     const ushort* __restrict__ U,
                                                     const ushort* __restrict__ Aw2,
                                                     float* __restrict__ out) {
    __shared__ ushort Xs[324 * 8];   // 5184 B
    __shared__ ushort As[5 * 2 * 64 * 8];
    __shared__ ushort Us[256 * 68];  // 34816 B
    const int b = blockIdx.y;
    const int ty = blockIdx.x >> 3, tx = blockIdx.x & 7;
    const int tid = threadIdx.x;
    const int wave = tid >> 6, lane = tid & 63;
    const int l31 = lane & 31, half = lane >> 5;

    for (int idx = tid; idx < 640; idx += 256)
        *(int4*)&As[idx * 8] = *(const int4*)(Aw2 + (size_t)idx * 8);
    for (int idx = tid; idx < 324; idx += 256) {
        int r = idx / 18, c = idx - r * 18;
        int gY = ty * 16 - 1 + r, gX = tx * 16 - 1 + c;
        int4 v = {0, 0, 0, 0};
        if ((unsigned)gY < 128u && (unsigned)gX < 128u)
            v = *(const int4*)(R1 + ((size_t)((b * 128 + gY) * 128 + gX)) * 8);
        *(int4*)&Xs[idx * 8] = v;
    }
    for (int idx = tid; idx < 2048; idx += 256) {
        int px = idx >> 3, q = idx & 7;
        int gY = ty * 16 + (px >> 4), gX = tx * 16 + (px & 15);
        const ushort* s = U + ((size_t)((b * 128 + gY) * 128 + gX)) * 64 + q * 8;
        ushort4 v0 = *(const ushort4*)s;
        ushort4 v1 = *(const ushort4*)(s + 4);
        *(ushort4*)&Us[px * 68 + q * 8] = v0;
        *(ushort4*)&Us[px * 68 + q * 8 + 4] = v1;
    }
    __syncthreads();

    f32x16 acc[2][2];
    #pragma unroll
    for (int mt = 0; mt < 2; mt++)
        #pragma unroll
        for (int nt = 0; nt < 2; nt++)
            #pragma unroll
            for (int r = 0; r < 16; r++) acc[mt][nt][r] = 0.f;

    #pragma unroll
    for (int s = 0; s < 5; s++) {
        bf16x8 a0 = *(const bf16x8*)&As[((s * 2 + 0) * 64 + lane) * 8];
        bf16x8 a1 = *(const bf16x8*)&As[((s * 2 + 1) * 64 + lane) * 8];
        int t = 2 * s + half;
        if (t > 8) t = 8;  // A is zero there
        int ky = t / 3, kx = t - ky * 3;
        #pragma unroll
        for (int nt = 0; nt < 2; nt++) {
            int pxl = wave * 64 + nt * 32 + l31;
            int row = pxl >> 4, col = pxl & 15;
            bf16x8 bv = *(const bf16x8*)&Xs[((row + ky) * 18 + col + kx) * 8];
            acc[0][nt] = __builtin_amdgcn_mfma_f32_32x32x16_bf16(a0, bv, acc[0][nt], 0, 0, 0);
            acc[1][nt] = __builtin_amdgcn_mfma_f32_32x32x16_bf16(a1, bv, acc[1][nt], 0, 0, 0);
        }
    }
    #pragma unroll
    for (int mt = 0; mt < 2; mt++) {
        #pragma unroll
        for (int nt = 0; nt < 2; nt++) {
            int pxl = wave * 64 + nt * 32 + l31;
            int gY = ty * 16 + (pxl >> 4), gX = tx * 16 + (pxl & 15);
            #pragma unroll
            for (int r = 0; r < 16; r++) {
                int o = mt * 32 + (r & 3) + 8 * (r >> 2) + 4 * half;
                float v = acc[mt][nt][r] + bf2f(Us[pxl * 68 + o]);
                out[((size_t)(b * 64 + o) * 128 + gY) * 128 + gX] = v;
            }
        }
    }
}

extern "C" void kernel_launch(void* const* d_in, const int* in_sizes, int n_in,
                              void* d_out, int out_size, void* d_ws, size_t ws_size,
                              hipStream_t stream) {
    const float* x1      = (const float*)d_in[0];
    const float* x2      = (const float*)d_in[1];
    const float* d1_w1   = (const float*)d_in[2];
    const float* d1_w2   = (const float*)d_in[3];
    const float* d2_w1   = (const float*)d_in[4];
    const float* d2_w2   = (const float*)d_in[5];
    const float* align_w = (const float*)d_in[6];
    const float* up_w1   = (const float*)d_in[7];
    const float* up_w2   = (const float*)d_in[8];
    const float* re_w1   = (const float*)d_in[9];
    const float* re_w2   = (const float*)d_in[10];
    float* out = (float*)d_out;
    float* ws  = (float*)d_ws;

    float*  pooled  = ws + OFF_POOLED;
    float*  pooled2 = ws + OFF_WK;
    ushort* Awt    = (ushort*)(ws + OFF_WT);
    ushort* Wf     = (ushort*)(ws + OFF_WF);
    ushort* Aw1    = (ushort*)(ws + OFF_AW1);
    ushort* Aw2    = (ushort*)(ws + OFF_AW2);
    ushort* bufT   = (ushort*)(ws + OFF_T);
    ushort* R1     = (ushort*)(ws + OFF_T);   // alias (bufT dead by re1)
    ushort* bufAB  = (ushort*)(ws + OFF_AB);
    ushort* bufU   = (ushort*)(ws + OFF_AB);  // alias (bufAB dead after align)
    ushort* F      = (ushort*)(ws + OFF_F);

    prep_kernel<<<201, 256, 0, stream>>>(up_w1, up_w2, Awt, align_w, Wf,
                                         re_w1, Aw1, re_w2, Aw2);
    pool_kernel<<<4096, 256, 0, stream>>>(x1, x2, pooled);
    dsc1_kernel<<<4096, 256, 0, stream>>>(x1, x2, pooled, d1_w1, d1_w2, bufT, pooled2);
    dsc2_kernel<<<4096, 256, 0, stream>>>(bufT, pooled2, d2_w1, d2_w2, bufAB);

    align_mfma_kernel<<<dim3(32, 16), 256, 0, stream>>>(bufAB, bufAB + 8388608, Wf, F);
    up_mfma_kernel<<<dim3(32, 16), 512, 0, stream>>>(F, Awt, bufU);
    re1_kernel<<<dim3(64, 16), 256, 0, stream>>>(bufU, Aw1, R1);
    re2_kernel<<<dim3(64, 16), 256, 0, stream>>>(R1, bufU, Aw2, out);
}

// Round 10
// 309.365 us; speedup vs baseline: 1.2290x; 1.2275x over previous
//
#include <hip/hip_runtime.h>
#include <math.h>

typedef unsigned short ushort;
typedef short bf16x8 __attribute__((ext_vector_type(8)));
typedef ushort us8 __attribute__((ext_vector_type(8)));
typedef float f32x16 __attribute__((ext_vector_type(16)));
typedef float f32x4 __attribute__((ext_vector_type(4)));

// ---------------- workspace layout (float elements) ----------------
static const size_t OFF_POOLED = 0;         // 4096 f (2 inputs x 2048)
static const size_t OFF_WK     = 4096;      // pooled2 (4096 f)
static const size_t OFF_WT     = 40960;     // Awt 294912 sh = 147456 f
static const size_t OFF_WF     = 188416;    // Wf 32768 sh = 16384 f
static const size_t OFF_AW1    = 204800;    // 9216 sh = 4608 f
static const size_t OFF_AW2    = 209408;    // 5120 sh = 2560 f
static const size_t OFF_T      = 262144;    // bufT 2x8M sh = 8388608 f ; R1 aliases
static const size_t OFF_AB     = 8650752;   // bufAB 2x8M sh = 8388608 f ; bufU aliases
static const size_t OFF_F      = 17039360;  // F 8388608 sh = 4194304 f
// total 21233664 f = 85 MB

static __device__ __forceinline__ ushort f2bf(float f) {
    unsigned int u = __builtin_bit_cast(unsigned int, f);
    u += 0x7FFF + ((u >> 16) & 1);
    return (ushort)(u >> 16);
}
static __device__ __forceinline__ float bf2f(ushort u) {
    return __builtin_bit_cast(float, ((unsigned int)u) << 16);
}

// ---------------- pool: tiny LDS so occupancy stays high --------------------
__global__ __launch_bounds__(256) void pool_kernel(const float* __restrict__ x1,
                                                   const float* __restrict__ x2,
                                                   float* __restrict__ pooled) {
    int bc = blockIdx.x;  // 4096
    const float* x = (bc >> 11) ? x2 : x1;
    const float4* p = (const float4*)(x + (size_t)(bc & 2047) * 4096);
    float s = 0.f;
    for (int i = threadIdx.x; i < 1024; i += 256) {
        float4 v = p[i];
        s += v.x + v.y + v.z + v.w;
    }
    #pragma unroll
    for (int off = 32; off; off >>= 1) s += __shfl_down(s, off);
    __shared__ float r4[4];
    if ((threadIdx.x & 63) == 0) r4[threadIdx.x >> 6] = s;
    __syncthreads();
    if (threadIdx.x == 0) pooled[bc] = (r4[0] + r4[1] + r4[2] + r4[3]) * (1.f / 4096.f);
}

// ---- prep: wcomb v3 (blocks 0..143, register GEMM) + awprep (144)
//      + aw1prep (145..180) + aw2prep (181..200) ----------------------------
// wcomb block (s=tap*8+c16, mh): out[o_sem, xcol] = sum_c w2[o_sem,c]*W1L[c,xcol]
//   xcol = (g>>1)*16 + (g&1)*8 + j, thread = (o_sem = t>>2, g = t&3), 8 j's.
// W1 staged by GATHERING only the needed 16KB (16 elems/thread).
// W2 staged float4, LDS stride 132 (16B-aligned; 2-way bank alias = free).
// Output: 8 j-consecutive ushorts -> one us8 store per thread.
__global__ __launch_bounds__(256) void prep_kernel(const float* __restrict__ up_w1,
                                                   const float* __restrict__ up_w2,
                                                   ushort* __restrict__ Awt,
                                                   const float* __restrict__ align_w,
                                                   ushort* __restrict__ Wf,
                                                   const float* __restrict__ re_w1,
                                                   ushort* __restrict__ Aw1,
                                                   const float* __restrict__ re_w2,
                                                   ushort* __restrict__ Aw2) {
    __shared__ float sm[12544];  // 50176 B: W2s[64*132] + W1L[128*32]
    const int bid = blockIdx.x;
    const int t = threadIdx.x;
    if (bid < 144) {
        // ---- wcomb v3 ----
        int mh = (bid >= 72) ? 1 : 0;
        int s = bid - mh * 72;
        int tap = s >> 3, c16 = s & 7;
        float* W2s = sm;          // [64][132]
        float* W1L = sm + 8448;   // [128][32]
        // stage W2: 2048 float4, 8 per thread
        #pragma unroll
        for (int k = 0; k < 8; k++) {
            int i4 = k * 256 + t;
            int o = i4 >> 5, c4 = (i4 & 31) * 4;
            *(float4*)&W2s[o * 132 + c4] = *(const float4*)&up_w2[o * 128 + c4];
        }
        // stage W1L: gather only needed elements (4096, 16 per thread)
        #pragma unroll
        for (int k = 0; k < 16; k++) {
            int i = k * 256 + t;
            int c = i >> 5, xcol = i & 31;
            int phl = xcol >> 4, cin = xcol & 15;
            int r = c * 4 + 2 * mh + phl;
            W1L[c * 32 + xcol] = up_w1[(size_t)r * 1152 + c16 * 144 + cin * 9 + tap];
        }
        __syncthreads();
        const int o = t >> 2, g = t & 3;
        float a0 = 0.f, a1 = 0.f, a2 = 0.f, a3 = 0.f;
        float a4 = 0.f, a5 = 0.f, a6 = 0.f, a7 = 0.f;
        const float* w2row = &W2s[o * 132];
        const float* xbase = &W1L[g * 8];
        #pragma unroll 4
        for (int c = 0; c < 128; c++) {
            float w = w2row[c];
            float4 xlo = *(const float4*)&xbase[c * 32];
            float4 xhi = *(const float4*)&xbase[c * 32 + 4];
            a0 += w * xlo.x; a1 += w * xlo.y; a2 += w * xlo.z; a3 += w * xlo.w;
            a4 += w * xhi.x; a5 += w * xhi.y; a6 += w * xhi.z; a7 += w * xhi.w;
        }
        // map (o, g) -> storage: mt = (g>>1)*2 + (o>>5), lane = (g&1)*32 + arow
        int o5 = o & 31;
        int arow = (o5 & 3) | (((o5 >> 4) & 1) << 2) | (((o5 >> 2) & 3) << 3);
        int mt = (g >> 1) * 2 + (o >> 5);
        int lane = (g & 1) * 32 + arow;
        us8 pk = {f2bf(a0), f2bf(a1), f2bf(a2), f2bf(a3),
                  f2bf(a4), f2bf(a5), f2bf(a6), f2bf(a7)};
        *(us8*)&Awt[(size_t)s * 4096 + mh * 2048 + mt * 512 + lane * 8] = pk;
    } else if (bid == 144) {
        // ---- awprep: Wf [step(16)][mt(4)][lane(64)][8] ----
        #pragma unroll 1
        for (int i = 0; i < 16; i++) {
            int tk = t + (i << 8);
            int step = tk >> 8, mt = (tk >> 6) & 3, lane = tk & 63;
            int o = mt * 32 + (lane & 31);
            int cb = step * 16 + (lane >> 5) * 8;
            #pragma unroll
            for (int j = 0; j < 8; j++) Wf[(size_t)tk * 8 + j] = f2bf(align_w[o * 256 + cb + j]);
        }
    } else if (bid < 181) {
        // ---- aw1prep ----
        int idx = (bid - 145) * 256 + t;  // < 9216
        if (idx < 9216) {
            int j = idx & 7, lane = (idx >> 3) & 63, s = idx >> 9;
            int m = lane & 15, kq = lane >> 4;
            int tap = s >> 1, ch = s & 1;
            int cin = ch * 32 + kq * 8 + j;
            float v = (m < 8) ? re_w1[((size_t)(m * 64 + cin)) * 9 + tap] : 0.f;
            Aw1[idx] = f2bf(v);
        }
    } else {
        // ---- aw2prep ----
        int idx = (bid - 181) * 256 + t;  // < 5120
        if (idx < 5120) {
            int j = idx & 7, lane = (idx >> 3) & 63, mt = (idx >> 9) & 1, s = idx >> 10;
            int m = mt * 32 + (lane & 31), half = lane >> 5;
            int k = s * 16 + half * 8 + j;
            int tap = k >> 3, c = k & 7;
            float v = (tap < 9) ? re_w2[((size_t)(m * 8 + c)) * 9 + tap] : 0.f;
            Aw2[idx] = f2bf(v);
        }
    }
}

// -------- dsc1: f32 in, bf16 out, relu+pool, wk computed inline -------------
__global__ __launch_bounds__(256) void dsc1_kernel(const float* __restrict__ x1,
                                                   const float* __restrict__ x2,
                                                   const float* __restrict__ pooled,
                                                   const float* __restrict__ w1,
                                                   const float* __restrict__ w2,
                                                   ushort* __restrict__ y,
                                                   float* __restrict__ pooled2) {
    int bc = blockIdx.x;  // 4096
    const float* xp = ((bc >> 11) ? x2 : x1) + (size_t)(bc & 2047) * 4096;
    ushort* yp = y + (size_t)bc * 4096;
    __shared__ float tile[66 * 66];
    __shared__ float r4[4];
    __shared__ float sp[128];
    __shared__ float sh[16];
    __shared__ float lgs[9];
    int t = threadIdx.x;
    if (t < 128) sp[t] = pooled[(bc >> 7) * 128 + t];
    for (int i = t; i < 66 * 66; i += 256) tile[i] = 0.f;
    __syncthreads();
    // gelu(pooled @ w1^T) by lanes 0..15, overlapped with tile fill
    if (t < 16) {
        float a = 0.f;
        #pragma unroll 4
        for (int c = 0; c < 128; c++) a += w1[t * 128 + c] * sp[c];
        sh[t] = 0.5f * a * (1.f + erff(a * 0.70710678118654752f));
    }
    const float4* xp4 = (const float4*)xp;
    for (int i = t; i < 1024; i += 256) {
        float4 v = xp4[i];
        int h = i >> 4, w = (i & 15) * 4;
        float* d = &tile[(h + 1) * 66 + w + 1];
        d[0] = v.x; d[1] = v.y; d[2] = v.z; d[3] = v.w;
    }
    __syncthreads();
    if (t < 9) {
        float a = 0.f;
        const float* wr = w2 + (size_t)((bc & 127) * 9 + t) * 16;
        #pragma unroll
        for (int r = 0; r < 16; r++) a += wr[r] * sh[r];
        lgs[t] = a;
    }
    __syncthreads();
    float kk[9];
    {
        float m = -INFINITY;
        #pragma unroll
        for (int k = 0; k < 9; k++) m = fmaxf(m, lgs[k]);
        float se = 0.f;
        #pragma unroll
        for (int k = 0; k < 9; k++) { kk[k] = expf(lgs[k] - m); se += kk[k]; }
        float inv = 1.f / se;
        #pragma unroll
        for (int k = 0; k < 9; k++) kk[k] *= inv;
    }
    float psum = 0.f;
    for (int i = t * 2; i < 4096; i += 512) {
        int h = i >> 6, w = i & 63;
        const float* c = &tile[h * 66 + w];
        float v0 = kk[0]*c[0] + kk[1]*c[1] + kk[2]*c[2]
                 + kk[3]*c[66] + kk[4]*c[67] + kk[5]*c[68]
                 + kk[6]*c[132] + kk[7]*c[133] + kk[8]*c[134] + c[67];
        float v1 = kk[0]*c[1] + kk[1]*c[2] + kk[2]*c[3]
                 + kk[3]*c[67] + kk[4]*c[68] + kk[5]*c[69]
                 + kk[6]*c[133] + kk[7]*c[134] + kk[8]*c[135] + c[68];
        v0 = fmaxf(v0, 0.f); v1 = fmaxf(v1, 0.f);
        psum += v0 + v1;
        ushort2 pk = {f2bf(v0), f2bf(v1)};
        *(ushort2*)&yp[i] = pk;
    }
    #pragma unroll
    for (int off = 32; off; off >>= 1) psum += __shfl_down(psum, off);
    if ((t & 63) == 0) r4[t >> 6] = psum;
    __syncthreads();
    if (t == 0) pooled2[bc] = (r4[0] + r4[1] + r4[2] + r4[3]) * (1.f / 4096.f);
}

// -------- dsc2: bf16 in, bf16 out, wk computed inline -----------------------
__global__ __launch_bounds__(256) void dsc2_kernel(const ushort* __restrict__ x,
                                                   const float* __restrict__ pooled,
                                                   const float* __restrict__ w1,
                                                   const float* __restrict__ w2,
                                                   ushort* __restrict__ y) {
    int bc = blockIdx.x;  // 4096
    const ushort* xp = x + (size_t)bc * 4096;
    ushort* yp = y + (size_t)bc * 4096;
    __shared__ float tile[66 * 66];
    __shared__ float sp[128];
    __shared__ float sh[16];
    __shared__ float lgs[9];
    int t = threadIdx.x;
    if (t < 128) sp[t] = pooled[(bc >> 7) * 128 + t];
    for (int i = t; i < 66 * 66; i += 256) tile[i] = 0.f;
    __syncthreads();
    if (t < 16) {
        float a = 0.f;
        #pragma unroll 4
        for (int c = 0; c < 128; c++) a += w1[t * 128 + c] * sp[c];
        sh[t] = 0.5f * a * (1.f + erff(a * 0.70710678118654752f));
    }
    for (int i = t; i < 512; i += 256) {
        int4 raw = *(const int4*)&xp[i * 8];
        const ushort* u = (const ushort*)&raw;
        int h = i >> 3, w = (i & 7) * 8;
        float* d = &tile[(h + 1) * 66 + w + 1];
        #pragma unroll
        for (int j = 0; j < 8; j++) d[j] = bf2f(u[j]);
    }
    __syncthreads();
    if (t < 9) {
        float a = 0.f;
        const float* wr = w2 + (size_t)((bc & 127) * 9 + t) * 16;
        #pragma unroll
        for (int r = 0; r < 16; r++) a += wr[r] * sh[r];
        lgs[t] = a;
    }
    __syncthreads();
    float kk[9];
    {
        float m = -INFINITY;
        #pragma unroll
        for (int k = 0; k < 9; k++) m = fmaxf(m, lgs[k]);
        float se = 0.f;
        #pragma unroll
        for (int k = 0; k < 9; k++) { kk[k] = expf(lgs[k] - m); se += kk[k]; }
        float inv = 1.f / se;
        #pragma unroll
        for (int k = 0; k < 9; k++) kk[k] *= inv;
    }
    for (int i = t * 2; i < 4096; i += 512) {
        int h = i >> 6, w = i & 63;
        const float* c = &tile[h * 66 + w];
        float v0 = kk[0]*c[0] + kk[1]*c[1] + kk[2]*c[2]
                 + kk[3]*c[66] + kk[4]*c[67] + kk[5]*c[68]
                 + kk[6]*c[132] + kk[7]*c[133] + kk[8]*c[134] + c[67];
        float v1 = kk[0]*c[1] + kk[1]*c[2] + kk[2]*c[3]
                 + kk[3]*c[67] + kk[4]*c[68] + kk[5]*c[69]
                 + kk[6]*c[133] + kk[7]*c[134] + kk[8]*c[135] + c[68];
        ushort2 pk = {f2bf(v0), f2bf(v1)};
        *(ushort2*)&yp[i] = pk;
    }
}

// ---- align: F[b][px][128c] = W @ concat(A,B), bf16 MFMA --------------------
__global__ __launch_bounds__(256, 2) void align_mfma_kernel(const ushort* __restrict__ A,
                                                            const ushort* __restrict__ Bv,
                                                            const ushort* __restrict__ Wf,
                                                            ushort* __restrict__ F) {
    __shared__ ushort Xs[2 * 128 * 8];
    const int b = blockIdx.y;
    const int px0 = blockIdx.x << 7;
    const int tid = threadIdx.x;
    const int wave = tid >> 6, lane = tid & 63;
    const int l31 = lane & 31, half = lane >> 5;

    f32x16 acc[4];
    #pragma unroll
    for (int mt = 0; mt < 4; mt++)
        #pragma unroll
        for (int r = 0; r < 16; r++) acc[mt][r] = 0.f;

    const int cg0 = tid >> 7, pxs0 = tid & 127;
    const int bfofs = (wave * 32 + l31) * 8 + half * 1024;

    for (int step = 0; step < 16; step++) {
        const ushort* src =
            (step < 8 ? A : Bv) + (((size_t)(b * 128 + (step & 7) * 16)) << 12) + px0;
        if (step) __syncthreads();
        #pragma unroll
        for (int q = 0; q < 2; q++) {
            int cg = cg0 + q * 2, px = pxs0;
            ushort v0 = src[((size_t)(cg * 4 + 0) << 12) + px];
            ushort v1 = src[((size_t)(cg * 4 + 1) << 12) + px];
            ushort v2 = src[((size_t)(cg * 4 + 2) << 12) + px];
            ushort v3 = src[((size_t)(cg * 4 + 3) << 12) + px];
            ushort4 pk = {v0, v1, v2, v3};
            *(ushort4*)&Xs[(cg >> 1) * 1024 + px * 8 + (cg & 1) * 4] = pk;
        }
        __syncthreads();
        bf16x8 bfrag = *(const bf16x8*)&Xs[bfofs];
        const bf16x8* wf = (const bf16x8*)(Wf + ((size_t)step * 4 * 64 + lane) * 8);
        #pragma unroll
        for (int mt = 0; mt < 4; mt++)
            acc[mt] = __builtin_amdgcn_mfma_f32_32x32x16_bf16(wf[mt * 64], bfrag, acc[mt], 0, 0, 0);
    }
    // epilogue: F[b][px][c]; o = mt*32 + half*4 + 8*g + i
    ushort* fp = F + ((size_t)(b * 4096 + px0 + wave * 32 + l31)) * 128;
    #pragma unroll
    for (int mt = 0; mt < 4; mt++) {
        #pragma unroll
        for (int g = 0; g < 4; g++) {
            ushort4 pk = {f2bf(acc[mt][g * 4 + 0]), f2bf(acc[mt][g * 4 + 1]),
                          f2bf(acc[mt][g * 4 + 2]), f2bf(acc[mt][g * 4 + 3])};
            *(ushort4*)(fp + mt * 32 + half * 4 + 8 * g) = pk;
        }
    }
}

// ------ up-conv: implicit GEMM 32x32x16 bf16, F[b,px,c] -> U[b,Y,X,64] ------
// 512 threads / 8 waves, acc[2][2] = 64 AGPR per wave, (512,4) -> 4 waves/SIMD.
// Wave (mh = w>>2, bmt = (w>>1)&1, nh = w&1) owns op-quarter x px-half.
// A: distance-2 global ping-pong; B: distance-2 swizzled-LDS ping-pong.
// Direct-store epilogue (wcomb semantic reorder). No barriers in main loop.
__global__ __launch_bounds__(512, 4) void up_mfma_kernel(const ushort* __restrict__ F,
                                                         const ushort* __restrict__ Awt,
                                                         ushort* __restrict__ U) {
    __shared__ ushort Xs[180 * 128];  // 46080 B
    const int b = blockIdx.y;
    const int tr = blockIdx.x >> 3, tc = blockIdx.x & 7;
    const int tid = threadIdx.x;
    const int wave = tid >> 6, lane = tid & 63;
    const int l31 = lane & 31, half = lane >> 5;
    const int mh = wave >> 2, bmt = (wave >> 1) & 1, nh = wave & 1;

    // stage whole 18x10 halo x 128c; unit q stored at slot q ^ (px&7)
    for (int idx = tid; idx < 2880; idx += 512) {
        int px = idx >> 4, q = idx & 15;
        int r = px / 10, c = px - r * 10;
        int gh = tr * 16 - 1 + r, gw = tc * 8 - 1 + c;
        int4 v = {0, 0, 0, 0};
        if ((unsigned)gh < 64u && (unsigned)gw < 64u)
            v = *(const int4*)(F + ((size_t)(b * 4096 + gh * 64 + gw)) * 128 + q * 8);
        *(int4*)&Xs[px * 128 + ((q ^ (px & 7)) << 3)] = v;
    }
    __syncthreads();

    f32x16 acc[2][2];
    #pragma unroll
    for (int mt = 0; mt < 2; mt++)
        #pragma unroll
        for (int nt = 0; nt < 2; nt++)
            #pragma unroll
            for (int r = 0; r < 16; r++) acc[mt][nt][r] = 0.f;

    int xpos[2];
    #pragma unroll
    for (int nt = 0; nt < 2; nt++) {
        int pxl = nh * 64 + nt * 32 + l31;
        xpos[nt] = (pxl >> 3) * 10 + (pxl & 7);
    }

    // A stream: element offset (s*8 + mh*4 + bmt*2 + mtl)*512 + lane*8
    const ushort* abase = Awt + (size_t)(mh * 4 + bmt * 2) * 512 + lane * 8;

    #define LDA(ss, mtl) (*(const bf16x8*)(abase + (size_t)(ss) * 4096 + (mtl) * 512))
    #define LDB(ss, nt) ({                                                   \
        int tap_ = (ss) >> 3, c16_ = (ss) & 7;                               \
        int ky_ = (tap_ * 11) >> 5;  /* tap/3 for 0..8 */                    \
        int kx_ = tap_ - ky_ * 3;                                            \
        int p_ = xpos[nt] + ky_ * 10 + kx_;                                  \
        int qq_ = c16_ * 2 + half;                                           \
        *(const bf16x8*)&Xs[p_ * 128 + ((qq_ ^ (p_ & 7)) << 3)];             \
    })

    bf16x8 A0[2], A1[2], B0[2], B1[2];
    A0[0] = LDA(0, 0); A0[1] = LDA(0, 1);
    A1[0] = LDA(1, 0); A1[1] = LDA(1, 1);
    B0[0] = LDB(0, 0); B0[1] = LDB(0, 1);
    B1[0] = LDB(1, 0); B1[1] = LDB(1, 1);

    #define SUBSTEP(ASET, BSET, sn)                                                  \
    {                                                                                \
        _Pragma("unroll")                                                            \
        for (int mt = 0; mt < 2; mt++) {                                             \
            acc[mt][0] = __builtin_amdgcn_mfma_f32_32x32x16_bf16(ASET[mt], BSET[0], acc[mt][0], 0, 0, 0); \
            acc[mt][1] = __builtin_amdgcn_mfma_f32_32x32x16_bf16(ASET[mt], BSET[1], acc[mt][1], 0, 0, 0); \
        }                                                                            \
        ASET[0] = LDA(sn, 0); ASET[1] = LDA(sn, 1);                                  \
        BSET[0] = LDB(sn, 0); BSET[1] = LDB(sn, 1);                                  \
    }

    #pragma unroll 2
    for (int s = 0; s < 70; s += 2) {
        SUBSTEP(A0, B0, s + 2)
        int s3 = (s + 3 < 72) ? s + 3 : 0;
        SUBSTEP(A1, B1, s3)
    }
    // s = 70, 71 (prefetches above were clamped; just consume)
    #pragma unroll
    for (int mt = 0; mt < 2; mt++) {
        acc[mt][0] = __builtin_amdgcn_mfma_f32_32x32x16_bf16(A0[mt], B0[0], acc[mt][0], 0, 0, 0);
        acc[mt][1] = __builtin_amdgcn_mfma_f32_32x32x16_bf16(A0[mt], B0[1], acc[mt][1], 0, 0, 0);
    }
    #pragma unroll
    for (int mt = 0; mt < 2; mt++) {
        acc[mt][0] = __builtin_amdgcn_mfma_f32_32x32x16_bf16(A1[mt], B1[0], acc[mt][0], 0, 0, 0);
        acc[mt][1] = __builtin_amdgcn_mfma_f32_32x32x16_bf16(A1[mt], B1[1], acc[mt][1], 0, 0, 0);
    }
    #undef SUBSTEP
    #undef LDA
    #undef LDB

    // direct epilogue: per (mtl,nt) two 16B stores of 8 consecutive channels
    // global mt = bmt*2 + mtl; Y = 2*(tr*16+h)+mh, X = 2*(tc*8+w)+bmt,
    // ch = 32*mtl + 16*half + r
    #pragma unroll
    for (int nt = 0; nt < 2; nt++) {
        int pxl = nh * 64 + nt * 32 + l31;
        int Y = 2 * (tr * 16 + (pxl >> 3)) + mh;
        int X = 2 * (tc * 8 + (pxl & 7)) + bmt;
        #pragma unroll
        for (int mt = 0; mt < 2; mt++) {
            ushort* up = U + ((size_t)((b * 128 + Y) * 128 + X)) * 64
                       + mt * 32 + half * 16;
            us8 p0, p1;
            #pragma unroll
            for (int i = 0; i < 8; i++) {
                p0[i] = f2bf(acc[mt][nt][i]);
                p1[i] = f2bf(acc[mt][nt][8 + i]);
            }
            *(us8*)up = p0;
            *(us8*)(up + 8) = p1;
        }
    }
}

// ------ re1: conv3x3(U,re_w1)+relu via 16x16x32 MFMA -> R1[b,Y,X,8] ---------
__global__ __launch_bounds__(256, 2) void re1_kernel(const ushort* __restrict__ U,
                                                     const ushort* __restrict__ Aw1,
                                                     ushort* __restrict__ R1) {
    __shared__ ushort Xs[324 * 72];  // 46656 B
    __shared__ ushort As[18 * 64 * 8];
    const int b = blockIdx.y;
    const int ty = blockIdx.x >> 3, tx = blockIdx.x & 7;
    const int tid = threadIdx.x;
    const int wave = tid >> 6, lane = tid & 63;
    const int m16 = lane & 15, kq = lane >> 4;

    for (int idx = tid; idx < 1152; idx += 256)
        *(int4*)&As[idx * 8] = *(const int4*)(Aw1 + (size_t)idx * 8);
    for (int idx = tid; idx < 2592; idx += 256) {
        int px = idx >> 3, q = idx & 7;
        int r = px / 18, c = px - r * 18;
        int gY = ty * 16 - 1 + r, gX = tx * 16 - 1 + c;
        int4 v = {0, 0, 0, 0};
        if ((unsigned)gY < 128u && (unsigned)gX < 128u)
            v = *(const int4*)(U + ((size_t)((b * 128 + gY) * 128 + gX)) * 64 + q * 8);
        *(int4*)&Xs[px * 72 + q * 8] = v;
    }
    __syncthreads();

    f32x4 acc[4];
    #pragma unroll
    for (int nt = 0; nt < 4; nt++)
        #pragma unroll
        for (int r = 0; r < 4; r++) acc[nt][r] = 0.f;

    #pragma unroll 1
    for (int s = 0; s < 18; s++) {
        bf16x8 a = *(const bf16x8*)&As[(s * 64 + lane) * 8];
        int tap = s >> 1, ch = s & 1;
        int ky = tap / 3, kx = tap - ky * 3;
        int xo = (ky * 18 + kx) * 72 + ch * 32 + kq * 8;
        #pragma unroll
        for (int nt = 0; nt < 4; nt++) {
            int row = wave * 4 + nt;
            bf16x8 bv = *(const bf16x8*)&Xs[(row * 18 + m16) * 72 + xo];
            acc[nt] = __builtin_amdgcn_mfma_f32_16x16x32_bf16(a, bv, acc[nt], 0, 0, 0);
        }
    }
    if (kq < 2) {
        #pragma unroll
        for (int nt = 0; nt < 4; nt++) {
            int gY = ty * 16 + wave * 4 + nt, gX = tx * 16 + m16;
            ushort4 pk = {f2bf(fmaxf(acc[nt][0], 0.f)), f2bf(fmaxf(acc[nt][1], 0.f)),
                          f2bf(fmaxf(acc[nt][2], 0.f)), f2bf(fmaxf(acc[nt][3], 0.f))};
            *(ushort4*)(R1 + ((size_t)((b * 128 + gY) * 128 + gX)) * 8 + kq * 4) = pk;
        }
    }
}

// ------ re2: conv3x3(R1,re_w2) + up  via 32x32x16 MFMA -> out f32 planar ----
__global__ __launch_bounds__(256, 2) void re2_kernel(const ushort* __restrict__ R1,
                                                     const ushort* __restrict__ U,
                                                     const ushort* __restrict__ Aw2,
                                                     float* __restrict__ out) {
    __shared__ ushort Xs[324 * 8];   // 5184 B
    __shared__ ushort As[5 * 2 * 64 * 8];
    __shared__ ushort Us[256 * 68];  // 34816 B
    const int b = blockIdx.y;
    const int ty = blockIdx.x >> 3, tx = blockIdx.x & 7;
    const int tid = threadIdx.x;
    const int wave = tid >> 6, lane = tid & 63;
    const int l31 = lane & 31, half = lane >> 5;

    for (int idx = tid; idx < 640; idx += 256)
        *(int4*)&As[idx * 8] = *(const int4*)(Aw2 + (size_t)idx * 8);
    for (int idx = tid; idx < 324; idx += 256) {
        int r = idx / 18, c = idx - r * 18;
        int gY = ty * 16 - 1 + r, gX = tx * 16 - 1 + c;
        int4 v = {0, 0, 0, 0};
        if ((unsigned)gY < 128u && (unsigned)gX < 128u)
            v = *(const int4*)(R1 + ((size_t)((b * 128 + gY) * 128 + gX)) * 8);
        *(int4*)&Xs[idx * 8] = v;
    }
    for (int idx = tid; idx < 2048; idx += 256) {
        int px = idx >> 3, q = idx & 7;
        int gY = ty * 16 + (px >> 4), gX = tx * 16 + (px & 15);
        const ushort* s = U + ((size_t)((b * 128 + gY) * 128 + gX)) * 64 + q * 8;
        ushort4 v0 = *(const ushort4*)s;
        ushort4 v1 = *(const ushort4*)(s + 4);
        *(ushort4*)&Us[px * 68 + q * 8] = v0;
        *(ushort4*)&Us[px * 68 + q * 8 + 4] = v1;
    }
    __syncthreads();

    f32x16 acc[2][2];
    #pragma unroll
    for (int mt = 0; mt < 2; mt++)
        #pragma unroll
        for (int nt = 0; nt < 2; nt++)
            #pragma unroll
            for (int r = 0; r < 16; r++) acc[mt][nt][r] = 0.f;

    #pragma unroll
    for (int s = 0; s < 5; s++) {
        bf16x8 a0 = *(const bf16x8*)&As[((s * 2 + 0) * 64 + lane) * 8];
        bf16x8 a1 = *(const bf16x8*)&As[((s * 2 + 1) * 64 + lane) * 8];
        int t = 2 * s + half;
        if (t > 8) t = 8;  // A is zero there
        int ky = t / 3, kx = t - ky * 3;
        #pragma unroll
        for (int nt = 0; nt < 2; nt++) {
            int pxl = wave * 64 + nt * 32 + l31;
            int row = pxl >> 4, col = pxl & 15;
            bf16x8 bv = *(const bf16x8*)&Xs[((row + ky) * 18 + col + kx) * 8];
            acc[0][nt] = __builtin_amdgcn_mfma_f32_32x32x16_bf16(a0, bv, acc[0][nt], 0, 0, 0);
            acc[1][nt] = __builtin_amdgcn_mfma_f32_32x32x16_bf16(a1, bv, acc[1][nt], 0, 0, 0);
        }
    }
    #pragma unroll
    for (int mt = 0; mt < 2; mt++) {
        #pragma unroll
        for (int nt = 0; nt < 2; nt++) {
            int pxl = wave * 64 + nt * 32 + l31;
            int gY = ty * 16 + (pxl >> 4), gX = tx * 16 + (pxl & 15);
            #pragma unroll
            for (int r = 0; r < 16; r++) {
                int o = mt * 32 + (r & 3) + 8 * (r >> 2) + 4 * half;
                float v = acc[mt][nt][r] + bf2f(Us[pxl * 68 + o]);
                out[((size_t)(b * 64 + o) * 128 + gY) * 128 + gX] = v;
            }
        }
    }
}

extern "C" void kernel_launch(void* const* d_in, const int* in_sizes, int n_in,
                              void* d_out, int out_size, void* d_ws, size_t ws_size,
                              hipStream_t stream) {
    const float* x1      = (const float*)d_in[0];
    const float* x2      = (const float*)d_in[1];
    const float* d1_w1   = (const float*)d_in[2];
    const float* d1_w2   = (const float*)d_in[3];
    const float* d2_w1   = (const float*)d_in[4];
    const float* d2_w2   = (const float*)d_in[5];
    const float* align_w = (const float*)d_in[6];
    const float* up_w1   = (const float*)d_in[7];
    const float* up_w2   = (const float*)d_in[8];
    const float* re_w1   = (const float*)d_in[9];
    const float* re_w2   = (const float*)d_in[10];
    float* out = (float*)d_out;
    float* ws  = (float*)d_ws;

    float*  pooled  = ws + OFF_POOLED;
    float*  pooled2 = ws + OFF_WK;
    ushort* Awt    = (ushort*)(ws + OFF_WT);
    ushort* Wf     = (ushort*)(ws + OFF_WF);
    ushort* Aw1    = (ushort*)(ws + OFF_AW1);
    ushort* Aw2    = (ushort*)(ws + OFF_AW2);
    ushort* bufT   = (ushort*)(ws + OFF_T);
    ushort* R1     = (ushort*)(ws + OFF_T);   // alias (bufT dead by re1)
    ushort* bufAB  = (ushort*)(ws + OFF_AB);
    ushort* bufU   = (ushort*)(ws + OFF_AB);  // alias (bufAB dead after align)
    ushort* F      = (ushort*)(ws + OFF_F);

    prep_kernel<<<201, 256, 0, stream>>>(up_w1, up_w2, Awt, align_w, Wf,
                                         re_w1, Aw1, re_w2, Aw2);
    pool_kernel<<<4096, 256, 0, stream>>>(x1, x2, pooled);
    dsc1_kernel<<<4096, 256, 0, stream>>>(x1, x2, pooled, d1_w1, d1_w2, bufT, pooled2);
    dsc2_kernel<<<4096, 256, 0, stream>>>(bufT, pooled2, d2_w1, d2_w2, bufAB);

    align_mfma_kernel<<<dim3(32, 16), 256, 0, stream>>>(bufAB, bufAB + 8388608, Wf, F);
    up_mfma_kernel<<<dim3(32, 16), 512, 0, stream>>>(F, Awt, bufU);
    re1_kernel<<<dim3(64, 16), 256, 0, stream>>>(bufU, Aw1, R1);
    re2_kernel<<<dim3(64, 16), 256, 0, stream>>>(R1, bufU, Aw2, out);
}